// Round 7
// baseline (292.056 us; speedup 1.0000x reference)
//
#include <hip/hip_runtime.h>
#include <math.h>

#define Bn 2
#define Hn 8
#define Nn 256
#define Dn 64
#define BH 16
#define SCALER 0.125f

typedef _Float16 half8 __attribute__((ext_vector_type(8)));
typedef _Float16 half4 __attribute__((ext_vector_type(4)));
typedef float floatx4 __attribute__((ext_vector_type(4)));

__device__ __forceinline__ void split_f32(float v, _Float16& h, _Float16& l) {
    h = (_Float16)v;
    l = (_Float16)(v - (float)h);
}

__device__ __forceinline__ void split8(const float4& v0, const float4& v1,
                                       half8& h, half8& l) {
    const float vv[8] = {v0.x, v0.y, v0.z, v0.w, v1.x, v1.y, v1.z, v1.w};
    #pragma unroll
    for (int e = 0; e < 8; ++e) {
        _Float16 hh, ll;
        split_f32(vv[e], hh, ll);
        h[e] = hh; l[e] = ll;
    }
}

__device__ __forceinline__ void gload_lds16(const float* g, void* lds_base) {
    __builtin_amdgcn_global_load_lds(
        (const __attribute__((address_space(1))) unsigned int*)g,
        (__attribute__((address_space(3))) unsigned int*)lds_base, 16, 0, 0);
}

// ---------------------------------------------------------------------------
// Fused split of x (blocks 0..255) and w (blocks 256..1535) to f16 hi/lo.
// ---------------------------------------------------------------------------
__global__ __launch_bounds__(256) void split2_kernel(
    const float* __restrict__ x, const float* __restrict__ w,
    _Float16* __restrict__ xh, _Float16* __restrict__ xl,
    _Float16* __restrict__ wh, _Float16* __restrict__ wl) {
    const int b = blockIdx.x;
    const float* src;
    _Float16 *hp, *lp;
    int idx;
    if (b < 256) {
        idx = (b * 256 + threadIdx.x) * 4;
        src = x; hp = xh; lp = xl;
    } else {
        idx = ((b - 256) * 256 + threadIdx.x) * 4;
        src = w; hp = wh; lp = wl;
    }
    const float4 v = *(const float4*)(src + idx);
    half4 hh, ll;
    _Float16 a2, b2;
    split_f32(v.x, a2, b2); hh[0] = a2; ll[0] = b2;
    split_f32(v.y, a2, b2); hh[1] = a2; ll[1] = b2;
    split_f32(v.z, a2, b2); hh[2] = a2; ll[2] = b2;
    split_f32(v.w, a2, b2); hh[3] = a2; ll[3] = b2;
    *(half4*)(hp + idx) = hh;
    *(half4*)(lp + idx) = ll;
}

// ---------------------------------------------------------------------------
// Projection, pre-split inputs, pure loads. Tile 64m x 64r, grid (8, 40).
// Blocks with blockIdx.y >= 32 (s=4, vk) write vkT directly (R13).
// ---------------------------------------------------------------------------
__global__ __launch_bounds__(256) void proj_mfma(
    const _Float16* __restrict__ xh, const _Float16* __restrict__ xl,
    const _Float16* __restrict__ wh, const _Float16* __restrict__ wl,
    float* __restrict__ P32, float* __restrict__ vkT) {
    const int m0 = blockIdx.x * 64;
    const int r0 = blockIdx.y * 64;
    const int t = threadIdx.x;
    const int w = t >> 6, l = t & 63;
    const int lr = l & 15, kk8 = (l >> 4) * 8;

    floatx4 acc[4];
    #pragma unroll
    for (int ni = 0; ni < 4; ++ni) acc[ni] = (floatx4){0.f, 0.f, 0.f, 0.f};

    const int arow = m0 + w * 16 + lr;
    for (int kt = 0; kt < 16; ++kt) {
        const int k0 = kt * 32 + kk8;
        const half8 ah = *(const half8*)(xh + arow * 512 + k0);
        const half8 al = *(const half8*)(xl + arow * 512 + k0);
        half8 bhv[4], blv[4];
        #pragma unroll
        for (int ni = 0; ni < 4; ++ni) {
            const int wr = r0 + ni * 16 + lr;
            bhv[ni] = *(const half8*)(wh + wr * 512 + k0);
            blv[ni] = *(const half8*)(wl + wr * 512 + k0);
        }
        #pragma unroll
        for (int ni = 0; ni < 4; ++ni)
            acc[ni] = __builtin_amdgcn_mfma_f32_16x16x32_f16(ah, bhv[ni], acc[ni], 0, 0, 0);
        #pragma unroll
        for (int ni = 0; ni < 4; ++ni)
            acc[ni] = __builtin_amdgcn_mfma_f32_16x16x32_f16(ah, blv[ni], acc[ni], 0, 0, 0);
        #pragma unroll
        for (int ni = 0; ni < 4; ++ni)
            acc[ni] = __builtin_amdgcn_mfma_f32_16x16x32_f16(al, bhv[ni], acc[ni], 0, 0, 0);
    }
    const int rbase = (l >> 4) * 4;
    if (blockIdx.y >= 32) {
        const int mbase = m0 + w * 16 + rbase;
        const int b = mbase >> 8, n = mbase & 255;
        #pragma unroll
        for (int ni = 0; ni < 4; ++ni) {
            const int rcol = r0 + ni * 16 + lr;
            const int h = (rcol >> 6) & 7, d = rcol & 63;
            *(float4*)(vkT + (((b * 8 + h) * 64 + d) * 256 + n)) =
                (float4){acc[ni][0], acc[ni][1], acc[ni][2], acc[ni][3]};
        }
        return;
    }
    #pragma unroll
    for (int ni = 0; ni < 4; ++ni) {
        const int rcol = r0 + ni * 16 + lr;
        const int s = rcol >> 9, h = (rcol >> 6) & 7, d = rcol & 63;
        #pragma unroll
        for (int r = 0; r < 4; ++r) {
            const int m = m0 + w * 16 + rbase + r;
            const int b = m >> 8, n = m & 255;
            P32[(((s * 2 + b) * 8 + h) * 256 + n) * 64 + d] = acc[ni][r];
        }
    }
}

// ---------------------------------------------------------------------------
// Scores + fused exp. Stabilization shifts dropped (cancel exactly).
// ---------------------------------------------------------------------------
__global__ __launch_bounds__(256) void score_vkt(
    const float* __restrict__ P32,
    _Float16* __restrict__ Xsh, _Float16* __restrict__ Xsl,
    float* __restrict__ Yt, float* __restrict__ Z) {
    const int bh = blockIdx.x, mat = blockIdx.y;
    const int t = threadIdx.x;
    const int i0 = (blockIdx.z >> 2) * 128;
    const int j0 = (blockIdx.z & 3) * 64;
    const int w = t >> 6, l = t & 63;
    const int lr = l & 15, kk8 = (l >> 4) * 8;
    const float* A;
    const float* Bm;
    if (mat == 0)      { A = P32 + (1 * 16 + bh) * 16384; Bm = P32 + (2 * 16 + bh) * 16384; }
    else if (mat == 1) { A = P32 + (0 * 16 + bh) * 16384; Bm = P32 + (2 * 16 + bh) * 16384; }
    else               { A = P32 + (0 * 16 + bh) * 16384; Bm = P32 + (1 * 16 + bh) * 16384; }

    floatx4 acc[2][4];
    #pragma unroll
    for (int mi = 0; mi < 2; ++mi)
        #pragma unroll
        for (int ni = 0; ni < 4; ++ni) acc[mi][ni] = (floatx4){0.f, 0.f, 0.f, 0.f};

    for (int kt = 0; kt < 2; ++kt) {
        const int k0 = kt * 32 + kk8;
        half8 ah[2], al[2], bh8[4], bl8[4];
        #pragma unroll
        for (int mi = 0; mi < 2; ++mi) {
            const int row = i0 + w * 32 + mi * 16 + lr;
            const float4 v0 = *(const float4*)(A + row * 64 + k0);
            const float4 v1 = *(const float4*)(A + row * 64 + k0 + 4);
            split8(v0, v1, ah[mi], al[mi]);
        }
        #pragma unroll
        for (int ni = 0; ni < 4; ++ni) {
            const int row = j0 + ni * 16 + lr;
            const float4 v0 = *(const float4*)(Bm + row * 64 + k0);
            const float4 v1 = *(const float4*)(Bm + row * 64 + k0 + 4);
            split8(v0, v1, bh8[ni], bl8[ni]);
        }
        #pragma unroll
        for (int mi = 0; mi < 2; ++mi)
            #pragma unroll
            for (int ni = 0; ni < 4; ++ni)
                acc[mi][ni] = __builtin_amdgcn_mfma_f32_16x16x32_f16(ah[mi], bh8[ni], acc[mi][ni], 0, 0, 0);
        #pragma unroll
        for (int mi = 0; mi < 2; ++mi)
            #pragma unroll
            for (int ni = 0; ni < 4; ++ni)
                acc[mi][ni] = __builtin_amdgcn_mfma_f32_16x16x32_f16(ah[mi], bl8[ni], acc[mi][ni], 0, 0, 0);
        #pragma unroll
        for (int mi = 0; mi < 2; ++mi)
            #pragma unroll
            for (int ni = 0; ni < 4; ++ni)
                acc[mi][ni] = __builtin_amdgcn_mfma_f32_16x16x32_f16(al[mi], bh8[ni], acc[mi][ni], 0, 0, 0);
    }
    const int rbase = (l >> 4) * 4;
    #pragma unroll
    for (int mi = 0; mi < 2; ++mi)
        #pragma unroll
        for (int ni = 0; ni < 4; ++ni)
            #pragma unroll
            for (int r = 0; r < 4; ++r) {
                const int row = i0 + w * 32 + mi * 16 + rbase + r;
                const int col = j0 + ni * 16 + lr;
                const float e = expf(acc[mi][ni][r] * SCALER);
                if (mat == 0) {
                    const int idx = (bh * 256 + row) * 256 + col;
                    _Float16 hh, ll; split_f32(e, hh, ll);
                    Xsh[idx] = hh; Xsl[idx] = ll;
                } else if (mat == 1) {
                    Yt[bh * 65536 + row * 256 + col] = e;
                } else {
                    Z[bh * 65536 + row * 256 + col] = e;
                }
            }
}

// ---------------------------------------------------------------------------
// Den. grid (16,16): bh x 16-row i-tile. 4 waves split 16 jt-groups.
// ---------------------------------------------------------------------------
__global__ __launch_bounds__(256) void den_mfma(
    const float* __restrict__ Yt, const _Float16* __restrict__ Xh,
    const _Float16* __restrict__ Xl, const float* __restrict__ Z,
    float* __restrict__ Den) {
    const int bh = blockIdx.x;
    const int ibase = blockIdx.y * 16;
    const int t = threadIdx.x;
    const int w = t >> 6, l = t & 63;
    const int lr = l & 15, ks = l >> 4, kk8 = ks * 8;
    const float* Ytp = Yt + bh * 65536;
    const _Float16* Xhp = Xh + bh * 65536;
    const _Float16* Xlp = Xl + bh * 65536;

    floatx4 acc[4];
    #pragma unroll
    for (int q = 0; q < 4; ++q) acc[q] = (floatx4){0.f, 0.f, 0.f, 0.f};

    for (int kt = 0; kt < 8; ++kt) {
        const int k0 = kt * 32 + kk8;
        half8 ah, al;
        {
            const float4 v0 = *(const float4*)(Ytp + (ibase + lr) * 256 + k0);
            const float4 v1 = *(const float4*)(Ytp + (ibase + lr) * 256 + k0 + 4);
            split8(v0, v1, ah, al);
        }
        half8 bh8[4], bl8[4];
        #pragma unroll
        for (int q = 0; q < 4; ++q) {
            const int jt = w * 4 + q;
            bh8[q] = *(const half8*)(Xhp + (jt * 16 + lr) * 256 + k0);
            bl8[q] = *(const half8*)(Xlp + (jt * 16 + lr) * 256 + k0);
        }
        #pragma unroll
        for (int q = 0; q < 4; ++q)
            acc[q] = __builtin_amdgcn_mfma_f32_16x16x32_f16(ah, bh8[q], acc[q], 0, 0, 0);
        #pragma unroll
        for (int q = 0; q < 4; ++q)
            acc[q] = __builtin_amdgcn_mfma_f32_16x16x32_f16(ah, bl8[q], acc[q], 0, 0, 0);
        #pragma unroll
        for (int q = 0; q < 4; ++q)
            acc[q] = __builtin_amdgcn_mfma_f32_16x16x32_f16(al, bh8[q], acc[q], 0, 0, 0);
    }
    __shared__ float redS[4][16];
    float dp[4] = {0.f, 0.f, 0.f, 0.f};
    const float* Zp = Z + (bh * 256 + ibase) * 256;
    #pragma unroll
    for (int q = 0; q < 4; ++q) {
        const int jt = w * 4 + q;
        #pragma unroll
        for (int r = 0; r < 4; ++r)
            dp[r] += acc[q][r] * Zp[(ks * 4 + r) * 256 + jt * 16 + lr];
    }
    #pragma unroll
    for (int r = 0; r < 4; ++r) {
        float s = dp[r];
        s += __shfl_xor(s, 1); s += __shfl_xor(s, 2);
        s += __shfl_xor(s, 4); s += __shfl_xor(s, 8);
        if (lr == 0) redS[w][ks * 4 + r] = s;
    }
    __syncthreads();
    if (t < 16)
        Den[bh * 256 + ibase + t] =
            redS[0][t] + redS[1][t] + redS[2][t] + redS[3][t] + 1e-9f;
}

// ---------------------------------------------------------------------------
// Main contraction — R14: G=1 (one i per block, 4096 blocks), drain-safe
// 2-phase schedule. Rationale:
//  * R8's 2-wave/SIMD ceiling is registers: acc 128 + A-dbuf 64. G=1 gives
//    acc[4][4]=64, A single-buffer 32 + in-flight prefetch 32, BSTORE ~40
//    transient -> peak ~140 <= 170 -> __launch_bounds__(256,3).
//  * RAW is filled by cross-wave global_load_lds DMA; vmcnt is per-wave, so
//    any consumer must sit behind {own-wave drain -> barrier}. R11/R12 raced
//    exactly here. This kernel drains fully at every barrier (__syncthreads),
//    with every load issued a full phase before its drain point.
//  * Step: STAGE(kt+2) | BSTORE(kt+1) | LOADA(kt+1) | MFMA(kt) | syncthreads.
// ---------------------------------------------------------------------------
__global__ __launch_bounds__(256, 3) void attn_mfma(
    const _Float16* __restrict__ Xh, const _Float16* __restrict__ Xl,
    const float* __restrict__ Yt, const float* __restrict__ Z,
    const float* __restrict__ vkT, const float* __restrict__ P32,
    const float* __restrict__ Den, float* __restrict__ out) {
    const int id = (blockIdx.x & 7) * 512 + (blockIdx.x >> 3);  // XCD swizzle (8*512)
    const int bh = id >> 8;
    const int i = id & 255;
    const int t = threadIdx.x;
    const int w = t >> 6, l = t & 63;
    const int lr = l & 15, ks = l >> 4, kk8 = ks * 8;

    __shared__ float yiS[256], ziS[256];
    __shared__ float RAW[2][2048];                 // raw vk f32 tile (64d x 32k)
    __shared__ _Float16 BhS[2][2048], BlS[2][2048];
    __shared__ float redN[4][64];

    yiS[t] = Yt[(bh * 256 + i) * 256 + t];
    ziS[t] = Z[(bh * 256 + i) * 256 + t];

    const _Float16* Xhp = Xh + bh * 65536;
    const _Float16* Xlp = Xl + bh * 65536;
    const float* vkp = vkT + bh * 16384;
    const float* vj = P32 + (3 * 16 + bh) * 16384;

    floatx4 acc[4][4];
    #pragma unroll
    for (int mi = 0; mi < 4; ++mi)
        #pragma unroll
        for (int ct = 0; ct < 4; ++ct) acc[mi][ct] = (floatx4){0.f, 0.f, 0.f, 0.f};

    // BSTORE thread mapping: 64 d x 4 k-octets = 256 threads, 8 elems each
    const int bd = t >> 2;            // d row 0..63
    const int sl = t & 3;             // k-octet 0..3 within 32-k tile
    const int uhf2 = sl >> 1;         // k-half (16 f32) of the octet
    const int g0 = (2 * sl) & 3, g1 = (2 * sl + 1) & 3;

    // ---- STAGE: raw vk tile kts -> RAW[kts&1] via global_load_lds (as R8)
    auto STAGE = [&](int kts) {
        const int k0 = (kts & 7) * 32;
        const int buf = kts & 1;
        #pragma unroll
        for (int q = 0; q < 2; ++q) {
            const int u = q * 256 + t;
            const int g = u >> 7, ubd = (u & 127) >> 1, uhf = u & 1;
            const float* gp = vkp + ubd * 256 + k0 + uhf * 16 + g * 4;
            void* lp = (char*)&RAW[buf][0] + q * 4096 + w * 1024;  // wave-uniform
            gload_lds16(gp, lp);
        }
    };
    // ---- BSTORE: RAW[ktb&1] -> *y -> split -> swizzled BhS/BlS[ktb&1]
    auto BSTORE = [&](int ktb) {
        const int buf = ktb & 1;
        const float* yrow = &yiS[(ktb & 7) * 32 + sl * 8];
        // RAW[(g*128 + d*2 + uhf)*4 + e] = vk[d][uhf*16 + g*4 + e]
        const float4 v0 = *(float4*)&RAW[buf][(g0 * 128 + bd * 2 + uhf2) * 4];
        const float4 v1 = *(float4*)&RAW[buf][(g1 * 128 + bd * 2 + uhf2) * 4];
        const float4 y0 = *(const float4*)(yrow);
        const float4 y1 = *(const float4*)(yrow + 4);
        const float pv[8] = {v0.x * y0.x, v0.y * y0.y, v0.z * y0.z, v0.w * y0.w,
                             v1.x * y1.x, v1.y * y1.y, v1.z * y1.z, v1.w * y1.w};
        half8 hv, lv;
        #pragma unroll
        for (int e = 0; e < 8; ++e) {
            _Float16 hh, ll;
            split_f32(pv[e], hh, ll);
            hv[e] = hh; lv[e] = ll;
        }
        const int off = ((bd * 4 + sl) ^ ((bd >> 1) & 7)) * 8;
        *(half8*)&BhS[buf][off] = hv;
        *(half8*)&BlS[buf][off] = lv;
    };
    auto LOADA = [&](half8* AH, half8* AL, int kt) {
        const int k0 = (kt & 7) * 32 + kk8;
        #pragma unroll
        for (int mi = 0; mi < 4; ++mi) {
            const int row = w * 64 + mi * 16 + lr;
            AH[mi] = *(const half8*)(Xhp + row * 256 + k0);
            AL[mi] = *(const half8*)(Xlp + row * 256 + k0);
        }
    };
    auto MFMA_STEP = [&](half8* AH, half8* AL, int buf) {
        __builtin_amdgcn_s_setprio(1);
        #pragma unroll
        for (int ct = 0; ct < 4; ++ct) {
            const int dd = ct * 16 + lr;
            const int off = ((dd * 4 + ks) ^ ((dd >> 1) & 7)) * 8;
            const half8 bhf = *(const half8*)&BhS[buf][off];
            const half8 blf = *(const half8*)&BlS[buf][off];
            #pragma unroll
            for (int mi = 0; mi < 4; ++mi)
                acc[mi][ct] = __builtin_amdgcn_mfma_f32_16x16x32_f16(AH[mi], bhf, acc[mi][ct], 0, 0, 0);
            #pragma unroll
            for (int mi = 0; mi < 4; ++mi)
                acc[mi][ct] = __builtin_amdgcn_mfma_f32_16x16x32_f16(AH[mi], blf, acc[mi][ct], 0, 0, 0);
            #pragma unroll
            for (int mi = 0; mi < 4; ++mi)
                acc[mi][ct] = __builtin_amdgcn_mfma_f32_16x16x32_f16(AL[mi], bhf, acc[mi][ct], 0, 0, 0);
        }
        __builtin_amdgcn_s_setprio(0);
    };

    half8 Aah[4], Aal[4], Abh[4], Abl[4];

    // ---- prologue: stage k-tiles 0,1; load A(0); build B(0)
    STAGE(0);
    STAGE(1);
    LOADA(Aah, Aal, 0);
    __syncthreads();                 // full drain: yiS/ziS, RAW(0), RAW(1) visible
    BSTORE(0);
    __syncthreads();                 // B(0) ready

    // ---- main loop: 8 steps, one __syncthreads per step (full drain)
    #pragma unroll 1
    for (int kq = 0; kq < 4; ++kq) {
        const int kt = kq * 2;
        // even step (buf 0): uses Aa, prefetches Ab
        if (kt < 6) STAGE(kt + 2);
        BSTORE(kt + 1);
        LOADA(Abh, Abl, kt + 1);
        MFMA_STEP(Aah, Aal, 0);
        __syncthreads();
        // odd step (buf 1): uses Ab, prefetches Aa
        if (kt + 1 < 6) STAGE(kt + 3);
        if (kt + 1 < 7) BSTORE(kt + 2);
        LOADA(Aah, Aal, (kt + 2) & 7);
        MFMA_STEP(Abh, Abl, 1);
        __syncthreads();
    }

    // ---- epilogue: Num_d = sum_j acc * z[j] * vj[j][d], reduce over ks groups
    float z0[16];
    #pragma unroll
    for (int mi = 0; mi < 4; ++mi)
        #pragma unroll
        for (int r = 0; r < 4; ++r)
            z0[mi * 4 + r] = ziS[w * 64 + mi * 16 + ks * 4 + r];
    #pragma unroll
    for (int ct = 0; ct < 4; ++ct) {
        float n = 0.f;
        #pragma unroll
        for (int mi = 0; mi < 4; ++mi)
            #pragma unroll
            for (int r = 0; r < 4; ++r) {
                const int j = w * 64 + mi * 16 + ks * 4 + r;
                n += acc[mi][ct][r] * z0[mi * 4 + r] * vj[j * 64 + ct * 16 + lr];
            }
        n += __shfl_xor(n, 16); n += __shfl_xor(n, 32);
        if (l < 16) redN[w][ct * 16 + l] = n;
    }
    __syncthreads();
    if (t < 64) {
        const float num = redN[0][t] + redN[1][t] + redN[2][t] + redN[3][t];
        const float den = Den[bh * 256 + i];
        out[((bh >> 3) * 256 + i) * 512 + (bh & 7) * 64 + t] = num / den;
    }
}

extern "C" void kernel_launch(void* const* d_in, const int* in_sizes, int n_in,
                              void* d_out, int out_size, void* d_ws, size_t ws_size,
                              hipStream_t stream) {
    const float* x = (const float*)d_in[0];
    const float* w = (const float*)d_in[1];
    float* out = (float*)d_out;

    float* ws = (float*)d_ws;
    float* P32 = ws;                                    // 1,310,720 f32
    float* U = ws + 1310720;
    // epoch A (proj inputs, dead after proj):
    _Float16* xh = (_Float16*)U;
    _Float16* xl = xh + 262144;
    _Float16* wh = xl + 262144;
    _Float16* wl = wh + 1310720;
    // epoch B (score onward):
    _Float16* Xsh = (_Float16*)U;                       // 1,048,576 h
    _Float16* Xsl = Xsh + 1048576;
    float* Yt = U + 1048576;                            // 1,048,576 f32
    float* Z = Yt + 1048576;                            // 1,048,576 f32
    float* vkT = Z + 1048576;                           // 262,144 f32 (written by proj)
    float* Den = vkT + 262144;                          // 4,096 f32

    split2_kernel<<<1536, 256, 0, stream>>>(x, w, xh, xl, wh, wl);
    proj_mfma<<<dim3(8, 40), 256, 0, stream>>>(xh, xl, wh, wl, P32, vkT);
    score_vkt<<<dim3(16, 3, 8), 256, 0, stream>>>(P32, Xsh, Xsl, Yt, Z);
    den_mfma<<<dim3(16, 16), 256, 0, stream>>>(Yt, Xsh, Xsl, Z, Den);
    attn_mfma<<<4096, 256, 0, stream>>>(Xsh, Xsl, Yt, Z, vkT, P32, Den, out);
}

// Round 8
// 221.038 us; speedup vs baseline: 1.3213x; 1.3213x over previous
//
#include <hip/hip_runtime.h>
#include <math.h>

#define Bn 2
#define Hn 8
#define Nn 256
#define Dn 64
#define BH 16
#define SCALER 0.125f

typedef _Float16 half8 __attribute__((ext_vector_type(8)));
typedef _Float16 half4 __attribute__((ext_vector_type(4)));
typedef float floatx4 __attribute__((ext_vector_type(4)));

__device__ __forceinline__ void split_f32(float v, _Float16& h, _Float16& l) {
    h = (_Float16)v;
    l = (_Float16)(v - (float)h);
}

__device__ __forceinline__ void split8(const float4& v0, const float4& v1,
                                       half8& h, half8& l) {
    const float vv[8] = {v0.x, v0.y, v0.z, v0.w, v1.x, v1.y, v1.z, v1.w};
    #pragma unroll
    for (int e = 0; e < 8; ++e) {
        _Float16 hh, ll;
        split_f32(vv[e], hh, ll);
        h[e] = hh; l[e] = ll;
    }
}

__device__ __forceinline__ void gload_lds16(const float* g, void* lds_base) {
    __builtin_amdgcn_global_load_lds(
        (const __attribute__((address_space(1))) unsigned int*)g,
        (__attribute__((address_space(3))) unsigned int*)lds_base, 16, 0, 0);
}

// ---------------------------------------------------------------------------
// Fused split of x (blocks 0..255) and w (blocks 256..1535) to f16 hi/lo.
// ---------------------------------------------------------------------------
__global__ __launch_bounds__(256) void split2_kernel(
    const float* __restrict__ x, const float* __restrict__ w,
    _Float16* __restrict__ xh, _Float16* __restrict__ xl,
    _Float16* __restrict__ wh, _Float16* __restrict__ wl) {
    const int b = blockIdx.x;
    const float* src;
    _Float16 *hp, *lp;
    int idx;
    if (b < 256) {
        idx = (b * 256 + threadIdx.x) * 4;
        src = x; hp = xh; lp = xl;
    } else {
        idx = ((b - 256) * 256 + threadIdx.x) * 4;
        src = w; hp = wh; lp = wl;
    }
    const float4 v = *(const float4*)(src + idx);
    half4 hh, ll;
    _Float16 a2, b2;
    split_f32(v.x, a2, b2); hh[0] = a2; ll[0] = b2;
    split_f32(v.y, a2, b2); hh[1] = a2; ll[1] = b2;
    split_f32(v.z, a2, b2); hh[2] = a2; ll[2] = b2;
    split_f32(v.w, a2, b2); hh[3] = a2; ll[3] = b2;
    *(half4*)(hp + idx) = hh;
    *(half4*)(lp + idx) = ll;
}

// ---------------------------------------------------------------------------
// Projection, pre-split inputs, pure loads. Tile 64m x 64r, grid (8, 40).
// Blocks with blockIdx.y >= 32 (s=4, vk) write vkT directly (R13).
// ---------------------------------------------------------------------------
__global__ __launch_bounds__(256) void proj_mfma(
    const _Float16* __restrict__ xh, const _Float16* __restrict__ xl,
    const _Float16* __restrict__ wh, const _Float16* __restrict__ wl,
    float* __restrict__ P32, float* __restrict__ vkT) {
    const int m0 = blockIdx.x * 64;
    const int r0 = blockIdx.y * 64;
    const int t = threadIdx.x;
    const int w = t >> 6, l = t & 63;
    const int lr = l & 15, kk8 = (l >> 4) * 8;

    floatx4 acc[4];
    #pragma unroll
    for (int ni = 0; ni < 4; ++ni) acc[ni] = (floatx4){0.f, 0.f, 0.f, 0.f};

    const int arow = m0 + w * 16 + lr;
    for (int kt = 0; kt < 16; ++kt) {
        const int k0 = kt * 32 + kk8;
        const half8 ah = *(const half8*)(xh + arow * 512 + k0);
        const half8 al = *(const half8*)(xl + arow * 512 + k0);
        half8 bhv[4], blv[4];
        #pragma unroll
        for (int ni = 0; ni < 4; ++ni) {
            const int wr = r0 + ni * 16 + lr;
            bhv[ni] = *(const half8*)(wh + wr * 512 + k0);
            blv[ni] = *(const half8*)(wl + wr * 512 + k0);
        }
        #pragma unroll
        for (int ni = 0; ni < 4; ++ni)
            acc[ni] = __builtin_amdgcn_mfma_f32_16x16x32_f16(ah, bhv[ni], acc[ni], 0, 0, 0);
        #pragma unroll
        for (int ni = 0; ni < 4; ++ni)
            acc[ni] = __builtin_amdgcn_mfma_f32_16x16x32_f16(ah, blv[ni], acc[ni], 0, 0, 0);
        #pragma unroll
        for (int ni = 0; ni < 4; ++ni)
            acc[ni] = __builtin_amdgcn_mfma_f32_16x16x32_f16(al, bhv[ni], acc[ni], 0, 0, 0);
    }
    const int rbase = (l >> 4) * 4;
    if (blockIdx.y >= 32) {
        const int mbase = m0 + w * 16 + rbase;
        const int b = mbase >> 8, n = mbase & 255;
        #pragma unroll
        for (int ni = 0; ni < 4; ++ni) {
            const int rcol = r0 + ni * 16 + lr;
            const int h = (rcol >> 6) & 7, d = rcol & 63;
            *(float4*)(vkT + (((b * 8 + h) * 64 + d) * 256 + n)) =
                (float4){acc[ni][0], acc[ni][1], acc[ni][2], acc[ni][3]};
        }
        return;
    }
    #pragma unroll
    for (int ni = 0; ni < 4; ++ni) {
        const int rcol = r0 + ni * 16 + lr;
        const int s = rcol >> 9, h = (rcol >> 6) & 7, d = rcol & 63;
        #pragma unroll
        for (int r = 0; r < 4; ++r) {
            const int m = m0 + w * 16 + rbase + r;
            const int b = m >> 8, n = m & 255;
            P32[(((s * 2 + b) * 8 + h) * 256 + n) * 64 + d] = acc[ni][r];
        }
    }
}

// ---------------------------------------------------------------------------
// Scores + fused exp. Stabilization shifts dropped (cancel exactly).
// ---------------------------------------------------------------------------
__global__ __launch_bounds__(256) void score_vkt(
    const float* __restrict__ P32,
    _Float16* __restrict__ Xsh, _Float16* __restrict__ Xsl,
    float* __restrict__ Yt, float* __restrict__ Z) {
    const int bh = blockIdx.x, mat = blockIdx.y;
    const int t = threadIdx.x;
    const int i0 = (blockIdx.z >> 2) * 128;
    const int j0 = (blockIdx.z & 3) * 64;
    const int w = t >> 6, l = t & 63;
    const int lr = l & 15, kk8 = (l >> 4) * 8;
    const float* A;
    const float* Bm;
    if (mat == 0)      { A = P32 + (1 * 16 + bh) * 16384; Bm = P32 + (2 * 16 + bh) * 16384; }
    else if (mat == 1) { A = P32 + (0 * 16 + bh) * 16384; Bm = P32 + (2 * 16 + bh) * 16384; }
    else               { A = P32 + (0 * 16 + bh) * 16384; Bm = P32 + (1 * 16 + bh) * 16384; }

    floatx4 acc[2][4];
    #pragma unroll
    for (int mi = 0; mi < 2; ++mi)
        #pragma unroll
        for (int ni = 0; ni < 4; ++ni) acc[mi][ni] = (floatx4){0.f, 0.f, 0.f, 0.f};

    for (int kt = 0; kt < 2; ++kt) {
        const int k0 = kt * 32 + kk8;
        half8 ah[2], al[2], bh8[4], bl8[4];
        #pragma unroll
        for (int mi = 0; mi < 2; ++mi) {
            const int row = i0 + w * 32 + mi * 16 + lr;
            const float4 v0 = *(const float4*)(A + row * 64 + k0);
            const float4 v1 = *(const float4*)(A + row * 64 + k0 + 4);
            split8(v0, v1, ah[mi], al[mi]);
        }
        #pragma unroll
        for (int ni = 0; ni < 4; ++ni) {
            const int row = j0 + ni * 16 + lr;
            const float4 v0 = *(const float4*)(Bm + row * 64 + k0);
            const float4 v1 = *(const float4*)(Bm + row * 64 + k0 + 4);
            split8(v0, v1, bh8[ni], bl8[ni]);
        }
        #pragma unroll
        for (int mi = 0; mi < 2; ++mi)
            #pragma unroll
            for (int ni = 0; ni < 4; ++ni)
                acc[mi][ni] = __builtin_amdgcn_mfma_f32_16x16x32_f16(ah[mi], bh8[ni], acc[mi][ni], 0, 0, 0);
        #pragma unroll
        for (int mi = 0; mi < 2; ++mi)
            #pragma unroll
            for (int ni = 0; ni < 4; ++ni)
                acc[mi][ni] = __builtin_amdgcn_mfma_f32_16x16x32_f16(ah[mi], bl8[ni], acc[mi][ni], 0, 0, 0);
        #pragma unroll
        for (int mi = 0; mi < 2; ++mi)
            #pragma unroll
            for (int ni = 0; ni < 4; ++ni)
                acc[mi][ni] = __builtin_amdgcn_mfma_f32_16x16x32_f16(al[mi], bh8[ni], acc[mi][ni], 0, 0, 0);
    }
    const int rbase = (l >> 4) * 4;
    #pragma unroll
    for (int mi = 0; mi < 2; ++mi)
        #pragma unroll
        for (int ni = 0; ni < 4; ++ni)
            #pragma unroll
            for (int r = 0; r < 4; ++r) {
                const int row = i0 + w * 32 + mi * 16 + rbase + r;
                const int col = j0 + ni * 16 + lr;
                const float e = expf(acc[mi][ni][r] * SCALER);
                if (mat == 0) {
                    const int idx = (bh * 256 + row) * 256 + col;
                    _Float16 hh, ll; split_f32(e, hh, ll);
                    Xsh[idx] = hh; Xsl[idx] = ll;
                } else if (mat == 1) {
                    Yt[bh * 65536 + row * 256 + col] = e;
                } else {
                    Z[bh * 65536 + row * 256 + col] = e;
                }
            }
}

// ---------------------------------------------------------------------------
// Den. grid (16,16): bh x 16-row i-tile. 4 waves split 16 jt-groups.
// ---------------------------------------------------------------------------
__global__ __launch_bounds__(256) void den_mfma(
    const float* __restrict__ Yt, const _Float16* __restrict__ Xh,
    const _Float16* __restrict__ Xl, const float* __restrict__ Z,
    float* __restrict__ Den) {
    const int bh = blockIdx.x;
    const int ibase = blockIdx.y * 16;
    const int t = threadIdx.x;
    const int w = t >> 6, l = t & 63;
    const int lr = l & 15, ks = l >> 4, kk8 = ks * 8;
    const float* Ytp = Yt + bh * 65536;
    const _Float16* Xhp = Xh + bh * 65536;
    const _Float16* Xlp = Xl + bh * 65536;

    floatx4 acc[4];
    #pragma unroll
    for (int q = 0; q < 4; ++q) acc[q] = (floatx4){0.f, 0.f, 0.f, 0.f};

    for (int kt = 0; kt < 8; ++kt) {
        const int k0 = kt * 32 + kk8;
        half8 ah, al;
        {
            const float4 v0 = *(const float4*)(Ytp + (ibase + lr) * 256 + k0);
            const float4 v1 = *(const float4*)(Ytp + (ibase + lr) * 256 + k0 + 4);
            split8(v0, v1, ah, al);
        }
        half8 bh8[4], bl8[4];
        #pragma unroll
        for (int q = 0; q < 4; ++q) {
            const int jt = w * 4 + q;
            bh8[q] = *(const half8*)(Xhp + (jt * 16 + lr) * 256 + k0);
            bl8[q] = *(const half8*)(Xlp + (jt * 16 + lr) * 256 + k0);
        }
        #pragma unroll
        for (int q = 0; q < 4; ++q)
            acc[q] = __builtin_amdgcn_mfma_f32_16x16x32_f16(ah, bh8[q], acc[q], 0, 0, 0);
        #pragma unroll
        for (int q = 0; q < 4; ++q)
            acc[q] = __builtin_amdgcn_mfma_f32_16x16x32_f16(ah, bl8[q], acc[q], 0, 0, 0);
        #pragma unroll
        for (int q = 0; q < 4; ++q)
            acc[q] = __builtin_amdgcn_mfma_f32_16x16x32_f16(al, bh8[q], acc[q], 0, 0, 0);
    }
    __shared__ float redS[4][16];
    float dp[4] = {0.f, 0.f, 0.f, 0.f};
    const float* Zp = Z + (bh * 256 + ibase) * 256;
    #pragma unroll
    for (int q = 0; q < 4; ++q) {
        const int jt = w * 4 + q;
        #pragma unroll
        for (int r = 0; r < 4; ++r)
            dp[r] += acc[q][r] * Zp[(ks * 4 + r) * 256 + jt * 16 + lr];
    }
    #pragma unroll
    for (int r = 0; r < 4; ++r) {
        float s = dp[r];
        s += __shfl_xor(s, 1); s += __shfl_xor(s, 2);
        s += __shfl_xor(s, 4); s += __shfl_xor(s, 8);
        if (lr == 0) redS[w][ks * 4 + r] = s;
    }
    __syncthreads();
    if (t < 16)
        Den[bh * 256 + ibase + t] =
            redS[0][t] + redS[1][t] + redS[2][t] + redS[3][t] + 1e-9f;
}

// ---------------------------------------------------------------------------
// Main contraction — R15: R14's G=1 skeleton (passed correctness) with the
// two counter-diagnosed defects repaired:
//  * spill (R14 WRITE_SIZE 131 MB): A single-buffered (32 VGPR, no prefetch
//    arrays). Peak ~ acc 64 AGPR + A 32 + BSTORE transients ~32 + addr ~20
//    < 170 cap of __launch_bounds__(256,3).
//  * 1.05M bank conflicts: BSTORE uses R8's verified lane map
//    (bd=(t>>1)&63, hf=t&1) with R8's per-thread g-loop split across block
//    halves (gw=t>>7). RAW read addresses byte-identical to R8's
//    0-conflict pattern; same XOR swizzle on BhS/BlS.
// Full __syncthreads() drain per step (cross-wave DMA visibility — the
// R11/R12 race class is structurally excluded). 3 independent blocks/SIMD
// provide the cross-block overlap R8's 2-lockstep-wave layout lacked.
// ---------------------------------------------------------------------------
__global__ __launch_bounds__(256, 3) void attn_mfma(
    const _Float16* __restrict__ Xh, const _Float16* __restrict__ Xl,
    const float* __restrict__ Yt, const float* __restrict__ Z,
    const float* __restrict__ vkT, const float* __restrict__ P32,
    const float* __restrict__ Den, float* __restrict__ out) {
    const int id = (blockIdx.x & 7) * 512 + (blockIdx.x >> 3);  // XCD swizzle (8*512)
    const int bh = id >> 8;
    const int i = id & 255;
    const int t = threadIdx.x;
    const int w = t >> 6, l = t & 63;
    const int lr = l & 15, ks = l >> 4, kk8 = ks * 8;

    __shared__ float yiS[256], ziS[256];
    __shared__ float RAW[2][2048];                 // raw vk f32 tile (64d x 32k)
    __shared__ _Float16 BhS[2][2048], BlS[2][2048];
    __shared__ float redN[4][64];

    yiS[t] = Yt[(bh * 256 + i) * 256 + t];
    ziS[t] = Z[(bh * 256 + i) * 256 + t];

    const _Float16* Xhp = Xh + bh * 65536;
    const _Float16* Xlp = Xl + bh * 65536;
    const float* vkp = vkT + bh * 16384;
    const float* vj = P32 + (3 * 16 + bh) * 16384;

    floatx4 acc[4][4];
    #pragma unroll
    for (int mi = 0; mi < 4; ++mi)
        #pragma unroll
        for (int ct = 0; ct < 4; ++ct) acc[mi][ct] = (floatx4){0.f, 0.f, 0.f, 0.f};

    // BSTORE thread mapping (R8's, split across block halves):
    const int bd = (t >> 1) & 63;     // d row 0..63
    const int hf = t & 1;             // k-half (16 f32)
    const int gw = t >> 7;            // which g-pair of R8's per-thread loop

    // ---- STAGE: raw vk tile kts -> RAW[kts&1] via global_load_lds (R8 verbatim)
    auto STAGE = [&](int kts) {
        const int k0 = (kts & 7) * 32;
        const int buf = kts & 1;
        #pragma unroll
        for (int q = 0; q < 2; ++q) {
            const int u = q * 256 + t;
            const int g = u >> 7, ubd = (u & 127) >> 1, uhf = u & 1;
            const float* gp = vkp + ubd * 256 + k0 + uhf * 16 + g * 4;
            void* lp = (char*)&RAW[buf][0] + q * 4096 + w * 1024;  // wave-uniform
            gload_lds16(gp, lp);
        }
    };
    // ---- BSTORE: RAW[buf] -> *y -> split -> swizzled BhS/BlS[buf]
    //      (R8's math, one g-iteration per thread: g = gw)
    auto BSTORE = [&](int ktb) {
        const int buf = ktb & 1;
        const float* yrow = &yiS[(ktb & 7) * 32 + hf * 16 + gw * 8];
        const float4 v0 = *(float4*)&RAW[buf][(2 * gw) * 512 + bd * 8 + hf * 4];
        const float4 v1 = *(float4*)&RAW[buf][(2 * gw + 1) * 512 + bd * 8 + hf * 4];
        const float4 y0 = *(const float4*)(yrow);
        const float4 y1 = *(const float4*)(yrow + 4);
        const float pv[8] = {v0.x * y0.x, v0.y * y0.y, v0.z * y0.z, v0.w * y0.w,
                             v1.x * y1.x, v1.y * y1.y, v1.z * y1.z, v1.w * y1.w};
        half8 hv, lv;
        #pragma unroll
        for (int e = 0; e < 8; ++e) {
            _Float16 hh, ll;
            split_f32(pv[e], hh, ll);
            hv[e] = hh; lv[e] = ll;
        }
        const int off = ((bd * 4 + hf * 2 + gw) ^ ((bd >> 1) & 7)) * 8;
        *(half8*)&BhS[buf][off] = hv;
        *(half8*)&BlS[buf][off] = lv;
    };
    auto LOADA = [&](half8* AH, half8* AL, int kt) {
        const int k0 = (kt & 7) * 32 + kk8;
        #pragma unroll
        for (int mi = 0; mi < 4; ++mi) {
            const int row = w * 64 + mi * 16 + lr;
            AH[mi] = *(const half8*)(Xhp + row * 256 + k0);
            AL[mi] = *(const half8*)(Xlp + row * 256 + k0);
        }
    };
    auto MFMA_STEP = [&](half8* AH, half8* AL, int buf) {
        __builtin_amdgcn_s_setprio(1);
        #pragma unroll
        for (int ct = 0; ct < 4; ++ct) {
            const int dd = ct * 16 + lr;
            const int off = ((dd * 4 + ks) ^ ((dd >> 1) & 7)) * 8;
            const half8 bhf = *(const half8*)&BhS[buf][off];
            const half8 blf = *(const half8*)&BlS[buf][off];
            #pragma unroll
            for (int mi = 0; mi < 4; ++mi)
                acc[mi][ct] = __builtin_amdgcn_mfma_f32_16x16x32_f16(AH[mi], bhf, acc[mi][ct], 0, 0, 0);
            #pragma unroll
            for (int mi = 0; mi < 4; ++mi)
                acc[mi][ct] = __builtin_amdgcn_mfma_f32_16x16x32_f16(AH[mi], blf, acc[mi][ct], 0, 0, 0);
            #pragma unroll
            for (int mi = 0; mi < 4; ++mi)
                acc[mi][ct] = __builtin_amdgcn_mfma_f32_16x16x32_f16(AL[mi], bhf, acc[mi][ct], 0, 0, 0);
        }
        __builtin_amdgcn_s_setprio(0);
    };

    half8 Ah[4], Al[4];

    // ---- prologue: stage k-tiles 0,1; build B(0)
    STAGE(0);
    STAGE(1);
    __syncthreads();                 // full drain: yiS/ziS, RAW(0), RAW(1) visible
    BSTORE(0);
    __syncthreads();                 // B(0) ready

    // ---- main loop: 8 steps, one __syncthreads per step (full drain)
    #pragma unroll 1
    for (int kt = 0; kt < 8; ++kt) {
        LOADA(Ah, Al, kt);           // 8 vmem (oldest)
        if (kt < 6) STAGE(kt + 2);   // 2 vmem (newest)
        if (kt < 7) BSTORE(kt + 1);  // VALU/LDS hides LOADA latency
        if (kt < 6) {
            asm volatile("s_waitcnt vmcnt(2)" ::: "memory");  // LOADA done; STAGE may fly
        } else {
            asm volatile("s_waitcnt vmcnt(0)" ::: "memory");
        }
        __builtin_amdgcn_sched_barrier(0);
        MFMA_STEP(Ah, Al, kt & 1);
        __syncthreads();             // drains DMA + ds; next step's buffers safe
    }

    // ---- epilogue: Num_d = sum_j acc * z[j] * vj[j][d], reduce over ks groups
    float z0[16];
    #pragma unroll
    for (int mi = 0; mi < 4; ++mi)
        #pragma unroll
        for (int r = 0; r < 4; ++r)
            z0[mi * 4 + r] = ziS[w * 64 + mi * 16 + ks * 4 + r];
    #pragma unroll
    for (int ct = 0; ct < 4; ++ct) {
        float n = 0.f;
        #pragma unroll
        for (int mi = 0; mi < 4; ++mi)
            #pragma unroll
            for (int r = 0; r < 4; ++r) {
                const int j = w * 64 + mi * 16 + ks * 4 + r;
                n += acc[mi][ct][r] * z0[mi * 4 + r] * vj[j * 64 + ct * 16 + lr];
            }
        n += __shfl_xor(n, 16); n += __shfl_xor(n, 32);
        if (l < 16) redN[w][ct * 16 + l] = n;
    }
    __syncthreads();
    if (t < 64) {
        const float num = redN[0][t] + redN[1][t] + redN[2][t] + redN[3][t];
        const float den = Den[bh * 256 + i];
        out[((bh >> 3) * 256 + i) * 512 + (bh & 7) * 64 + t] = num / den;
    }
}

extern "C" void kernel_launch(void* const* d_in, const int* in_sizes, int n_in,
                              void* d_out, int out_size, void* d_ws, size_t ws_size,
                              hipStream_t stream) {
    const float* x = (const float*)d_in[0];
    const float* w = (const float*)d_in[1];
    float* out = (float*)d_out;

    float* ws = (float*)d_ws;
    float* P32 = ws;                                    // 1,310,720 f32
    float* U = ws + 1310720;
    // epoch A (proj inputs, dead after proj):
    _Float16* xh = (_Float16*)U;
    _Float16* xl = xh + 262144;
    _Float16* wh = xl + 262144;
    _Float16* wl = wh + 1310720;
    // epoch B (score onward):
    _Float16* Xsh = (_Float16*)U;                       // 1,048,576 h
    _Float16* Xsl = Xsh + 1048576;
    float* Yt = U + 1048576;                            // 1,048,576 f32
    float* Z = Yt + 1048576;                            // 1,048,576 f32
    float* vkT = Z + 1048576;                           // 262,144 f32 (written by proj)
    float* Den = vkT + 262144;                          // 4,096 f32

    split2_kernel<<<1536, 256, 0, stream>>>(x, w, xh, xl, wh, wl);
    proj_mfma<<<dim3(8, 40), 256, 0, stream>>>(xh, xl, wh, wl, P32, vkT);
    score_vkt<<<dim3(16, 3, 8), 256, 0, stream>>>(P32, Xsh, Xsl, Yt, Z);
    den_mfma<<<dim3(16, 16), 256, 0, stream>>>(Yt, Xsh, Xsl, Z, Den);
    attn_mfma<<<4096, 256, 0, stream>>>(Xsh, Xsl, Yt, Z, vkT, P32, Den, out);
}

// Round 9
// 169.417 us; speedup vs baseline: 1.7239x; 1.3047x over previous
//
#include <hip/hip_runtime.h>
#include <math.h>

#define Bn 2
#define Hn 8
#define Nn 256
#define Dn 64
#define BH 16
#define SCALER 0.125f

typedef _Float16 half8 __attribute__((ext_vector_type(8)));
typedef _Float16 half4 __attribute__((ext_vector_type(4)));
typedef float floatx4 __attribute__((ext_vector_type(4)));

__device__ __forceinline__ void split_f32(float v, _Float16& h, _Float16& l) {
    h = (_Float16)v;
    l = (_Float16)(v - (float)h);
}

__device__ __forceinline__ void split8(const float4& v0, const float4& v1,
                                       half8& h, half8& l) {
    const float vv[8] = {v0.x, v0.y, v0.z, v0.w, v1.x, v1.y, v1.z, v1.w};
    #pragma unroll
    for (int e = 0; e < 8; ++e) {
        _Float16 hh, ll;
        split_f32(vv[e], hh, ll);
        h[e] = hh; l[e] = ll;
    }
}

// ---------------------------------------------------------------------------
// Fused split of x (blocks 0..255) and w (blocks 256..1535) to f16 hi/lo.
// ---------------------------------------------------------------------------
__global__ __launch_bounds__(256) void split2_kernel(
    const float* __restrict__ x, const float* __restrict__ w,
    _Float16* __restrict__ xh, _Float16* __restrict__ xl,
    _Float16* __restrict__ wh, _Float16* __restrict__ wl) {
    const int b = blockIdx.x;
    const float* src;
    _Float16 *hp, *lp;
    int idx;
    if (b < 256) {
        idx = (b * 256 + threadIdx.x) * 4;
        src = x; hp = xh; lp = xl;
    } else {
        idx = ((b - 256) * 256 + threadIdx.x) * 4;
        src = w; hp = wh; lp = wl;
    }
    const float4 v = *(const float4*)(src + idx);
    half4 hh, ll;
    _Float16 a2, b2;
    split_f32(v.x, a2, b2); hh[0] = a2; ll[0] = b2;
    split_f32(v.y, a2, b2); hh[1] = a2; ll[1] = b2;
    split_f32(v.z, a2, b2); hh[2] = a2; ll[2] = b2;
    split_f32(v.w, a2, b2); hh[3] = a2; ll[3] = b2;
    *(half4*)(hp + idx) = hh;
    *(half4*)(lp + idx) = ll;
}

// ---------------------------------------------------------------------------
// Projection, pre-split inputs, pure loads. Tile 64m x 64r, grid (8, 40).
// Blocks with blockIdx.y >= 32 (s=4, vk) write vkT directly (R13).
// ---------------------------------------------------------------------------
__global__ __launch_bounds__(256) void proj_mfma(
    const _Float16* __restrict__ xh, const _Float16* __restrict__ xl,
    const _Float16* __restrict__ wh, const _Float16* __restrict__ wl,
    float* __restrict__ P32, float* __restrict__ vkT) {
    const int m0 = blockIdx.x * 64;
    const int r0 = blockIdx.y * 64;
    const int t = threadIdx.x;
    const int w = t >> 6, l = t & 63;
    const int lr = l & 15, kk8 = (l >> 4) * 8;

    floatx4 acc[4];
    #pragma unroll
    for (int ni = 0; ni < 4; ++ni) acc[ni] = (floatx4){0.f, 0.f, 0.f, 0.f};

    const int arow = m0 + w * 16 + lr;
    for (int kt = 0; kt < 16; ++kt) {
        const int k0 = kt * 32 + kk8;
        const half8 ah = *(const half8*)(xh + arow * 512 + k0);
        const half8 al = *(const half8*)(xl + arow * 512 + k0);
        half8 bhv[4], blv[4];
        #pragma unroll
        for (int ni = 0; ni < 4; ++ni) {
            const int wr = r0 + ni * 16 + lr;
            bhv[ni] = *(const half8*)(wh + wr * 512 + k0);
            blv[ni] = *(const half8*)(wl + wr * 512 + k0);
        }
        #pragma unroll
        for (int ni = 0; ni < 4; ++ni)
            acc[ni] = __builtin_amdgcn_mfma_f32_16x16x32_f16(ah, bhv[ni], acc[ni], 0, 0, 0);
        #pragma unroll
        for (int ni = 0; ni < 4; ++ni)
            acc[ni] = __builtin_amdgcn_mfma_f32_16x16x32_f16(ah, blv[ni], acc[ni], 0, 0, 0);
        #pragma unroll
        for (int ni = 0; ni < 4; ++ni)
            acc[ni] = __builtin_amdgcn_mfma_f32_16x16x32_f16(al, bhv[ni], acc[ni], 0, 0, 0);
    }
    const int rbase = (l >> 4) * 4;
    if (blockIdx.y >= 32) {
        const int mbase = m0 + w * 16 + rbase;
        const int b = mbase >> 8, n = mbase & 255;
        #pragma unroll
        for (int ni = 0; ni < 4; ++ni) {
            const int rcol = r0 + ni * 16 + lr;
            const int h = (rcol >> 6) & 7, d = rcol & 63;
            *(float4*)(vkT + (((b * 8 + h) * 64 + d) * 256 + n)) =
                (float4){acc[ni][0], acc[ni][1], acc[ni][2], acc[ni][3]};
        }
        return;
    }
    #pragma unroll
    for (int ni = 0; ni < 4; ++ni) {
        const int rcol = r0 + ni * 16 + lr;
        const int s = rcol >> 9, h = (rcol >> 6) & 7, d = rcol & 63;
        #pragma unroll
        for (int r = 0; r < 4; ++r) {
            const int m = m0 + w * 16 + rbase + r;
            const int b = m >> 8, n = m & 255;
            P32[(((s * 2 + b) * 8 + h) * 256 + n) * 64 + d] = acc[ni][r];
        }
    }
}

// ---------------------------------------------------------------------------
// Scores + fused exp. Stabilization shifts dropped (cancel exactly).
// ---------------------------------------------------------------------------
__global__ __launch_bounds__(256) void score_vkt(
    const float* __restrict__ P32,
    _Float16* __restrict__ Xsh, _Float16* __restrict__ Xsl,
    float* __restrict__ Yt, float* __restrict__ Z) {
    const int bh = blockIdx.x, mat = blockIdx.y;
    const int t = threadIdx.x;
    const int i0 = (blockIdx.z >> 2) * 128;
    const int j0 = (blockIdx.z & 3) * 64;
    const int w = t >> 6, l = t & 63;
    const int lr = l & 15, kk8 = (l >> 4) * 8;
    const float* A;
    const float* Bm;
    if (mat == 0)      { A = P32 + (1 * 16 + bh) * 16384; Bm = P32 + (2 * 16 + bh) * 16384; }
    else if (mat == 1) { A = P32 + (0 * 16 + bh) * 16384; Bm = P32 + (2 * 16 + bh) * 16384; }
    else               { A = P32 + (0 * 16 + bh) * 16384; Bm = P32 + (1 * 16 + bh) * 16384; }

    floatx4 acc[2][4];
    #pragma unroll
    for (int mi = 0; mi < 2; ++mi)
        #pragma unroll
        for (int ni = 0; ni < 4; ++ni) acc[mi][ni] = (floatx4){0.f, 0.f, 0.f, 0.f};

    for (int kt = 0; kt < 2; ++kt) {
        const int k0 = kt * 32 + kk8;
        half8 ah[2], al[2], bh8[4], bl8[4];
        #pragma unroll
        for (int mi = 0; mi < 2; ++mi) {
            const int row = i0 + w * 32 + mi * 16 + lr;
            const float4 v0 = *(const float4*)(A + row * 64 + k0);
            const float4 v1 = *(const float4*)(A + row * 64 + k0 + 4);
            split8(v0, v1, ah[mi], al[mi]);
        }
        #pragma unroll
        for (int ni = 0; ni < 4; ++ni) {
            const int row = j0 + ni * 16 + lr;
            const float4 v0 = *(const float4*)(Bm + row * 64 + k0);
            const float4 v1 = *(const float4*)(Bm + row * 64 + k0 + 4);
            split8(v0, v1, bh8[ni], bl8[ni]);
        }
        #pragma unroll
        for (int mi = 0; mi < 2; ++mi)
            #pragma unroll
            for (int ni = 0; ni < 4; ++ni)
                acc[mi][ni] = __builtin_amdgcn_mfma_f32_16x16x32_f16(ah[mi], bh8[ni], acc[mi][ni], 0, 0, 0);
        #pragma unroll
        for (int mi = 0; mi < 2; ++mi)
            #pragma unroll
            for (int ni = 0; ni < 4; ++ni)
                acc[mi][ni] = __builtin_amdgcn_mfma_f32_16x16x32_f16(ah[mi], bl8[ni], acc[mi][ni], 0, 0, 0);
        #pragma unroll
        for (int mi = 0; mi < 2; ++mi)
            #pragma unroll
            for (int ni = 0; ni < 4; ++ni)
                acc[mi][ni] = __builtin_amdgcn_mfma_f32_16x16x32_f16(al[mi], bh8[ni], acc[mi][ni], 0, 0, 0);
    }
    const int rbase = (l >> 4) * 4;
    #pragma unroll
    for (int mi = 0; mi < 2; ++mi)
        #pragma unroll
        for (int ni = 0; ni < 4; ++ni)
            #pragma unroll
            for (int r = 0; r < 4; ++r) {
                const int row = i0 + w * 32 + mi * 16 + rbase + r;
                const int col = j0 + ni * 16 + lr;
                const float e = expf(acc[mi][ni][r] * SCALER);
                if (mat == 0) {
                    const int idx = (bh * 256 + row) * 256 + col;
                    _Float16 hh, ll; split_f32(e, hh, ll);
                    Xsh[idx] = hh; Xsl[idx] = ll;
                } else if (mat == 1) {
                    Yt[bh * 65536 + row * 256 + col] = e;
                } else {
                    Z[bh * 65536 + row * 256 + col] = e;
                }
            }
}

// ---------------------------------------------------------------------------
// Den. grid (16,16): bh x 16-row i-tile. 4 waves split 16 jt-groups.
// ---------------------------------------------------------------------------
__global__ __launch_bounds__(256) void den_mfma(
    const float* __restrict__ Yt, const _Float16* __restrict__ Xh,
    const _Float16* __restrict__ Xl, const float* __restrict__ Z,
    float* __restrict__ Den) {
    const int bh = blockIdx.x;
    const int ibase = blockIdx.y * 16;
    const int t = threadIdx.x;
    const int w = t >> 6, l = t & 63;
    const int lr = l & 15, ks = l >> 4, kk8 = ks * 8;
    const float* Ytp = Yt + bh * 65536;
    const _Float16* Xhp = Xh + bh * 65536;
    const _Float16* Xlp = Xl + bh * 65536;

    floatx4 acc[4];
    #pragma unroll
    for (int q = 0; q < 4; ++q) acc[q] = (floatx4){0.f, 0.f, 0.f, 0.f};

    for (int kt = 0; kt < 8; ++kt) {
        const int k0 = kt * 32 + kk8;
        half8 ah, al;
        {
            const float4 v0 = *(const float4*)(Ytp + (ibase + lr) * 256 + k0);
            const float4 v1 = *(const float4*)(Ytp + (ibase + lr) * 256 + k0 + 4);
            split8(v0, v1, ah, al);
        }
        half8 bh8[4], bl8[4];
        #pragma unroll
        for (int q = 0; q < 4; ++q) {
            const int jt = w * 4 + q;
            bh8[q] = *(const half8*)(Xhp + (jt * 16 + lr) * 256 + k0);
            bl8[q] = *(const half8*)(Xlp + (jt * 16 + lr) * 256 + k0);
        }
        #pragma unroll
        for (int q = 0; q < 4; ++q)
            acc[q] = __builtin_amdgcn_mfma_f32_16x16x32_f16(ah, bh8[q], acc[q], 0, 0, 0);
        #pragma unroll
        for (int q = 0; q < 4; ++q)
            acc[q] = __builtin_amdgcn_mfma_f32_16x16x32_f16(ah, bl8[q], acc[q], 0, 0, 0);
        #pragma unroll
        for (int q = 0; q < 4; ++q)
            acc[q] = __builtin_amdgcn_mfma_f32_16x16x32_f16(al, bh8[q], acc[q], 0, 0, 0);
    }
    __shared__ float redS[4][16];
    float dp[4] = {0.f, 0.f, 0.f, 0.f};
    const float* Zp = Z + (bh * 256 + ibase) * 256;
    #pragma unroll
    for (int q = 0; q < 4; ++q) {
        const int jt = w * 4 + q;
        #pragma unroll
        for (int r = 0; r < 4; ++r)
            dp[r] += acc[q][r] * Zp[(ks * 4 + r) * 256 + jt * 16 + lr];
    }
    #pragma unroll
    for (int r = 0; r < 4; ++r) {
        float s = dp[r];
        s += __shfl_xor(s, 1); s += __shfl_xor(s, 2);
        s += __shfl_xor(s, 4); s += __shfl_xor(s, 8);
        if (lr == 0) redS[w][ks * 4 + r] = s;
    }
    __syncthreads();
    if (t < 16)
        Den[bh * 256 + ibase + t] =
            redS[0][t] + redS[1][t] + redS[2][t] + redS[3][t] + 1e-9f;
}

// ---------------------------------------------------------------------------
// Main contraction — R16: R8 decomposition (2048 blocks, 2 i's, acc[4][8],
// 2 waves/SIMD) with BK=64: 4 steps x 192-MFMA bursts instead of 8 x 96.
// R15 proved duty cycle tracks burst size per sync period, not wave count.
// RAW/global_load_lds DMA is REPLACED by register-staged vk (VKLOAD 4x
// dwordx4 at step top, vmcnt(16) before BSTORE) — kills the cross-wave DMA
// visibility hazard and frees LDS so BK=64 B-dbuf fits: BhS/BlS 64 KB +
// y/z 4 KB = 69.6 KB -> still 2 blocks/CU. Regs: acc 128 + A 2-subtile 64 +
// vkr 16 + temps ~30 = 238 <= 256 (R8-proven budget, launch_bounds(256,2)).
// B granule swizzle extended to 3 bits (o ^ (d&7)): <=2-way banks (free).
// MFMA order per accumulator identical to R8 -> bit-identical output.
// ---------------------------------------------------------------------------
__global__ __launch_bounds__(256, 2) void attn_mfma(
    const _Float16* __restrict__ Xh, const _Float16* __restrict__ Xl,
    const float* __restrict__ Yt, const float* __restrict__ Z,
    const float* __restrict__ vkT, const float* __restrict__ P32,
    const float* __restrict__ Den, float* __restrict__ out) {
    const int id = (blockIdx.x & 7) * 256 + (blockIdx.x >> 3);  // XCD swizzle
    const int bh = id >> 7;
    const int i0 = (id & 127) * 2;
    const int t = threadIdx.x;
    const int w = t >> 6, l = t & 63;
    const int lr = l & 15, ks = l >> 4, kk8 = ks * 8;

    __shared__ float yiS[2][256], ziS[2][256];                 // 4 KB
    __shared__ _Float16 BhS[2][2][4096], BlS[2][2][4096];      // 64 KB
    // redN aliases yiS (2 KB). Safe: last yiS read is BSTORE(3) in step 2,
    // which precedes step-2's __syncthreads; epilogue runs after that.
    float (*redN)[2][64] = reinterpret_cast<float (*)[2][64]>(&yiS[0][0]);

    yiS[0][t] = Yt[(bh * 256 + i0) * 256 + t];
    yiS[1][t] = Yt[(bh * 256 + i0 + 1) * 256 + t];
    ziS[0][t] = Z[(bh * 256 + i0) * 256 + t];
    ziS[1][t] = Z[(bh * 256 + i0 + 1) * 256 + t];

    const _Float16* Xhp = Xh + bh * 65536;
    const _Float16* Xlp = Xl + bh * 65536;
    const float* vkp = vkT + bh * 16384;
    const float* vj = P32 + (3 * 16 + bh) * 16384;

    floatx4 acc[4][8];
    #pragma unroll
    for (int mi = 0; mi < 4; ++mi)
        #pragma unroll
        for (int ct = 0; ct < 8; ++ct) acc[mi][ct] = (floatx4){0.f, 0.f, 0.f, 0.f};

    // VKLOAD/BSTORE thread map: d = t>>2 (64 rows), sl = t&3 (16-k slice)
    const int vd = t >> 2;
    const int sl = t & 3;
    float4 vkr[4];                        // in-flight vk slice (16 f32)

    // ---- VKLOAD: vk[vd][kt*64 + sl*16 .. +15] -> vkr (4 x dwordx4)
    auto VKLOAD = [&](int kt) {
        const float* gp = vkp + vd * 256 + (kt & 3) * 64 + sl * 16;
        #pragma unroll
        for (int q = 0; q < 4; ++q) vkr[q] = *(const float4*)(gp + q * 4);
    };
    // ---- BSTORE: vkr * y -> split -> swizzled BhS/BlS[(ktb)&1]
    auto BSTORE = [&](int ktb) {
        const int buf = ktb & 1;
        #pragma unroll
        for (int i = 0; i < 2; ++i) {
            const float* yrow = &yiS[i][(ktb & 3) * 64 + sl * 16];
            #pragma unroll
            for (int hq = 0; hq < 2; ++hq) {          // octet pair
                const float4 va = vkr[hq * 2], vb = vkr[hq * 2 + 1];
                const float4 ya = *(const float4*)(yrow + hq * 8);
                const float4 yb = *(const float4*)(yrow + hq * 8 + 4);
                const float pv[8] = {va.x * ya.x, va.y * ya.y, va.z * ya.z, va.w * ya.w,
                                     vb.x * yb.x, vb.y * yb.y, vb.z * yb.z, vb.w * yb.w};
                half8 hv, lv;
                #pragma unroll
                for (int e = 0; e < 8; ++e) {
                    _Float16 hh, ll;
                    split_f32(pv[e], hh, ll);
                    hv[e] = hh; lv[e] = ll;
                }
                const int o = sl * 2 + hq;            // k-octet 0..7 in 64-k tile
                const int g = vd * 8 + (o ^ (vd & 7));
                *(half8*)&BhS[buf][i][g * 8] = hv;
                *(half8*)&BlS[buf][i][g * 8] = lv;
            }
        }
    };
    auto LOADA = [&](half8* AH, half8* AL, int kt, int sub) {
        const int k0 = (kt & 3) * 64 + sub * 32 + kk8;
        #pragma unroll
        for (int mi = 0; mi < 4; ++mi) {
            const int row = w * 64 + mi * 16 + lr;
            AH[mi] = *(const half8*)(Xhp + row * 256 + k0);
            AL[mi] = *(const half8*)(Xlp + row * 256 + k0);
        }
    };
    auto MFMA_STEP = [&](half8* AH, half8* AL, int buf, int sub) {
        __builtin_amdgcn_s_setprio(1);
        #pragma unroll
        for (int ct = 0; ct < 8; ++ct) {
            const int ii = ct >> 2;
            const int dd = (ct & 3) * 16 + lr;
            const int o = sub * 4 + ks;
            const int g = dd * 8 + (o ^ (dd & 7));
            const half8 bhf = *(const half8*)&BhS[buf][ii][g * 8];
            const half8 blf = *(const half8*)&BlS[buf][ii][g * 8];
            #pragma unroll
            for (int mi = 0; mi < 4; ++mi)
                acc[mi][ct] = __builtin_amdgcn_mfma_f32_16x16x32_f16(AH[mi], bhf, acc[mi][ct], 0, 0, 0);
            #pragma unroll
            for (int mi = 0; mi < 4; ++mi)
                acc[mi][ct] = __builtin_amdgcn_mfma_f32_16x16x32_f16(AH[mi], blf, acc[mi][ct], 0, 0, 0);
            #pragma unroll
            for (int mi = 0; mi < 4; ++mi)
                acc[mi][ct] = __builtin_amdgcn_mfma_f32_16x16x32_f16(AL[mi], bhf, acc[mi][ct], 0, 0, 0);
        }
        __builtin_amdgcn_s_setprio(0);
    };

    half8 A0h[4], A0l[4], A1h[4], A1l[4];

    // ---- prologue: vk(0) in regs, A(0,sub0); build B(0)
    VKLOAD(0);                                   // 4 vmem
    LOADA(A0h, A0l, 0, 0);                       // 8 vmem
    asm volatile("s_waitcnt vmcnt(8)" ::: "memory");   // VKLOAD(0) + y/z loads done
    __builtin_amdgcn_sched_barrier(0);
    __syncthreads();                             // y/z ds_writes drained + visible
    BSTORE(0);
    __syncthreads();                             // B(0) visible

    // ---- main loop: steps 0..2 full; step 3 tail
    #pragma unroll 1
    for (int kt = 0; kt < 3; ++kt) {
        const int buf = kt & 1;
        VKLOAD(kt + 1);                          // 4 vmem
        LOADA(A1h, A1l, kt, 1);                  // 8 vmem
        MFMA_STEP(A0h, A0l, buf, 0);             // A0 from prev step (auto-wait)
        LOADA(A0h, A0l, kt + 1, 0);              // 8 vmem (next step's sub0)
        MFMA_STEP(A1h, A1l, buf, 1);             // A1 covered by sub0 burst
        asm volatile("s_waitcnt vmcnt(16)" ::: "memory");  // VKLOAD(kt+1) done
        __builtin_amdgcn_sched_barrier(0);
        BSTORE(kt + 1);                          // writes BhS[buf^1]
        __syncthreads();
    }
    // tail: kt = 3 (buf 1)
    LOADA(A1h, A1l, 3, 1);
    MFMA_STEP(A0h, A0l, 1, 0);
    MFMA_STEP(A1h, A1l, 1, 1);

    // ---- epilogue
    float z0[16], z1[16];
    #pragma unroll
    for (int mi = 0; mi < 4; ++mi)
        #pragma unroll
        for (int r = 0; r < 4; ++r) {
            const int j = w * 64 + mi * 16 + ks * 4 + r;
            z0[mi * 4 + r] = ziS[0][j];
            z1[mi * 4 + r] = ziS[1][j];
        }
    #pragma unroll
    for (int dt = 0; dt < 4; ++dt) {
        float n0 = 0.f, n1 = 0.f;
        #pragma unroll
        for (int mi = 0; mi < 4; ++mi)
            #pragma unroll
            for (int r = 0; r < 4; ++r) {
                const int j = w * 64 + mi * 16 + ks * 4 + r;
                const float v = vj[j * 64 + dt * 16 + lr];
                n0 += acc[mi][dt][r] * z0[mi * 4 + r] * v;
                n1 += acc[mi][dt + 4][r] * z1[mi * 4 + r] * v;
            }
        n0 += __shfl_xor(n0, 16); n0 += __shfl_xor(n0, 32);
        n1 += __shfl_xor(n1, 16); n1 += __shfl_xor(n1, 32);
        if (l < 16) {
            redN[w][0][dt * 16 + l] = n0;
            redN[w][1][dt * 16 + l] = n1;
        }
    }
    __syncthreads();
    if (t < 128) {
        const int ih = t >> 6, d = t & 63;
        const float num = redN[0][ih][d] + redN[1][ih][d] +
                          redN[2][ih][d] + redN[3][ih][d];
        const int i = i0 + ih;
        const float den = Den[bh * 256 + i];
        out[((bh >> 3) * 256 + i) * 512 + (bh & 7) * 64 + d] = num / den;
    }
}

extern "C" void kernel_launch(void* const* d_in, const int* in_sizes, int n_in,
                              void* d_out, int out_size, void* d_ws, size_t ws_size,
                              hipStream_t stream) {
    const float* x = (const float*)d_in[0];
    const float* w = (const float*)d_in[1];
    float* out = (float*)d_out;

    float* ws = (float*)d_ws;
    float* P32 = ws;                                    // 1,310,720 f32
    float* U = ws + 1310720;
    // epoch A (proj inputs, dead after proj):
    _Float16* xh = (_Float16*)U;
    _Float16* xl = xh + 262144;
    _Float16* wh = xl + 262144;
    _Float16* wl = wh + 1310720;
    // epoch B (score onward):
    _Float16* Xsh = (_Float16*)U;                       // 1,048,576 h
    _Float16* Xsl = Xsh + 1048576;
    float* Yt = U + 1048576;                            // 1,048,576 f32
    float* Z = Yt + 1048576;                            // 1,048,576 f32
    float* vkT = Z + 1048576;                           // 262,144 f32 (written by proj)
    float* Den = vkT + 262144;                          // 4,096 f32

    split2_kernel<<<1536, 256, 0, stream>>>(x, w, xh, xl, wh, wl);
    proj_mfma<<<dim3(8, 40), 256, 0, stream>>>(xh, xl, wh, wl, P32, vkT);
    score_vkt<<<dim3(16, 3, 8), 256, 0, stream>>>(P32, Xsh, Xsl, Yt, Z);
    den_mfma<<<dim3(16, 16), 256, 0, stream>>>(Yt, Xsh, Xsl, Z, Den);
    attn_mfma<<<2048, 256, 0, stream>>>(Xsh, Xsl, Yt, Z, vkT, P32, Den, out);
}